// Round 1
// baseline (130.386 us; speedup 1.0000x reference)
//
#include <hip/hip_runtime.h>

// ExtractTsFeatures fused, f16-packed end-to-end: x (512,1024,32) fp32 -> out (512,32,30) fp32.
// Block = 256 threads stages 8 series as f16 PAIRS (2 series per u32) into
// 16 KiB LDS; each wave owns one packed row = 2 series, 16 packed regs/lane.
// R0 changes vs previous best:
//  - exu/red_sum use mov_dpp (no tied-zero init) -> ~230 fewer v_mov per thread
//  - staging loads all 8 float4 first (32 VGPRs in flight), then converts:
//    breaks the serial per-wave HBM latency chain the 28-VGPR build had
//  - epilogue per-wave on lanes 0/1 (raw stats are wave-uniform SGPRs):
//    rawstash LDS + one __syncthreads removed

typedef _Float16 h2 __attribute__((ext_vector_type(2)));
typedef unsigned int uint;
typedef unsigned long long u64;

// constant lane-bit masks: bit set in lane l iff (l & BIT)
#define KM1  0xAAAAAAAAAAAAAAAAull
#define KM2  0xCCCCCCCCCCCCCCCCull
#define KM4  0xF0F0F0F0F0F0F0F0ull
#define KM8  0xFF00FF00FF00FF00ull
#define KM16 0xFFFF0000FFFF0000ull
#define KM32 0xFFFFFFFF00000000ull
#define KML0 0x0000000000000001ull   // lane 0 only
#define KML63 0x8000000000000000ull  // lane 63 only

__device__ __forceinline__ uint h2u(h2 v) { return __builtin_bit_cast(uint, v); }
__device__ __forceinline__ h2   u2h(uint v) { return __builtin_bit_cast(h2, v); }
__device__ __forceinline__ uint pkrtz(float a, float b) {
  return __builtin_bit_cast(uint, __builtin_amdgcn_cvt_pkrtz(a, b));
}
// pinned packed min/max (guarantee v_pk_*_f16)
__device__ __forceinline__ uint pmin(uint a, uint b) {
  uint r; asm("v_pk_min_f16 %0, %1, %2" : "=v"(r) : "v"(a), "v"(b)); return r;
}
__device__ __forceinline__ uint pmax(uint a, uint b) {
  uint r; asm("v_pk_max_f16 %0, %1, %2" : "=v"(r) : "v"(a), "v"(b)); return r;
}
// pinned per-lane select: lanes with mask-bit 1 take b, else a
__device__ __forceinline__ uint csel(uint a, uint b, u64 km) {
  uint r;
  asm("v_cndmask_b32 %0, %1, %2, %3" : "=v"(r) : "v"(a), "v"(b), "s"(km));
  return r;
}

// DPP mov without tied old operand (saves 1 v_mov per exchange).
#if __has_builtin(__builtin_amdgcn_mov_dpp)
#define DPPX(x, ctrl) ((uint)__builtin_amdgcn_mov_dpp((int)(x), ctrl, 0xF, 0xF, true))
#else
#define DPPX(x, ctrl) ((uint)__builtin_amdgcn_update_dpp(0, (int)(x), ctrl, 0xF, 0xF, true))
#endif

// xor-exchange on packed u32: DPP masks 1,2,3,7,8,15 (VALU); swizzle 4,16,31.
template <int MASK>
__device__ __forceinline__ uint exu(uint x) {
  static_assert(MASK == 1 || MASK == 2 || MASK == 3 || MASK == 4 || MASK == 7 ||
                MASK == 8 || MASK == 15 || MASK == 16 || MASK == 31, "bad mask");
  if constexpr (MASK == 1)  return DPPX(x, 0xB1);
  if constexpr (MASK == 2)  return DPPX(x, 0x4E);
  if constexpr (MASK == 3)  return DPPX(x, 0x1B);
  if constexpr (MASK == 7)  return DPPX(x, 0x141);
  if constexpr (MASK == 8)  return DPPX(x, 0x128);  // row_ror:8 == xor 8
  if constexpr (MASK == 15) return DPPX(x, 0x140);
  if constexpr (MASK == 4)  return (uint)__builtin_amdgcn_ds_swizzle((int)x, 0x101F);
  if constexpr (MASK == 16) return (uint)__builtin_amdgcn_ds_swizzle((int)x, 0x401F);
  if constexpr (MASK == 31) return (uint)__builtin_amdgcn_ds_swizzle((int)x, 0x7C1F);
  return x;
}

__device__ __forceinline__ uint bpermu(int addr, uint x) {
  return (uint)__builtin_amdgcn_ds_bpermute(addr, (int)x);
}
__device__ __forceinline__ uint irdl(uint v, int l) {
  return (uint)__builtin_amdgcn_readlane((int)v, l);
}

// packed f16 DPP tree sum (both series); result uniform via readlane 63.
__device__ __forceinline__ uint red_sum_pk(uint v) {
#define RSTEP(C) { uint t = DPPX(v, C); v = h2u(u2h(v) + u2h(t)); }
  RSTEP(0x111) RSTEP(0x112) RSTEP(0x114) RSTEP(0x118) RSTEP(0x142) RSTEP(0x143)
#undef RSTEP
  return irdl(v, 63);
}

// In-lane ascending bitonic sort of 16 packed pairs (compile-time directions).
__device__ __forceinline__ void sort16p(uint (&d)[16]) {
#pragma unroll
  for (int kk = 2; kk <= 16; kk <<= 1) {
#pragma unroll
    for (int j = kk >> 1; j >= 1; j >>= 1) {
#pragma unroll
      for (int r = 0; r < 16; ++r) {
        int p = r ^ j;
        if (p > r) {
          uint mn = pmin(d[r], d[p]);
          uint mx = pmax(d[r], d[p]);
          bool up = ((r & kk) == 0);
          d[r] = up ? mn : mx;
          d[p] = up ? mx : mn;
        }
      }
    }
  }
}
// In-lane ascending bitonic merge (j = 8..1).
__device__ __forceinline__ void merge16p(uint (&d)[16]) {
#pragma unroll
  for (int j = 8; j >= 1; j >>= 1) {
#pragma unroll
    for (int r = 0; r < 16; ++r) {
      int p = r ^ j;
      if (p > r) {
        uint mn = pmin(d[r], d[p]);
        d[p] = pmax(d[r], d[p]);
        d[r] = mn;
      }
    }
  }
}

// Split with reversal: pos m pairs with lane^MASK, reg 15-r.
template <int MASK>
__device__ __forceinline__ void splitp(uint (&d)[16], u64 km) {
#pragma unroll
  for (int r = 0; r < 8; ++r) {
    uint pa = exu<MASK>(d[15 - r]);
    uint pb = exu<MASK>(d[r]);
    uint mn0 = pmin(d[r], pa),      mx0 = pmax(d[r], pa);
    uint mn1 = pmin(d[15 - r], pb), mx1 = pmax(d[15 - r], pb);
    d[r]      = csel(mn0, mx0, km);
    d[15 - r] = csel(mn1, mx1, km);
  }
}
__device__ __forceinline__ void split63p(uint (&d)[16], u64 km, int addr63) {
#pragma unroll
  for (int r = 0; r < 8; ++r) {
    uint pa = bpermu(addr63, d[15 - r]);
    uint pb = bpermu(addr63, d[r]);
    uint mn0 = pmin(d[r], pa),      mx0 = pmax(d[r], pa);
    uint mn1 = pmin(d[15 - r], pb), mx1 = pmax(d[15 - r], pb);
    d[r]      = csel(mn0, mx0, km);
    d[15 - r] = csel(mn1, mx1, km);
  }
}
// Straight merge stage at lane distance MASK.
template <int MASK>
__device__ __forceinline__ void xstp(uint (&d)[16], u64 km) {
#pragma unroll
  for (int r = 0; r < 16; ++r) {
    uint t = exu<MASK>(d[r]);
    d[r] = csel(pmin(d[r], t), pmax(d[r], t), km);
  }
}

__global__ __launch_bounds__(256, 6) void feat_fused(const float* __restrict__ x,
                                                     float* __restrict__ out) {
  __shared__ __align__(16) uint sm[4 * 1024];  // 4 packed rows x 1024 = 16 KiB
  __shared__ float stash[8 * 30];              // per-block output stage (960 B)
  const int tid  = threadIdx.x;
  const int lane = tid & 63;
  const int wv   = tid >> 6;
  const int g    = blockIdx.x;
  const int b  = ((g & 7) << 6) + (g >> 5);   // XCD swizzle: siblings share L2
  const int f8 = (g >> 3) & 3;

  // ---- stage 8 series as 4 packed f16 rows (all loads in flight first) ----
  const float4* xv = (const float4*)x;
  const int fq = tid & 1, t0 = tid >> 1;
  const size_t base4 = (size_t)b * 8192 + (size_t)((f8 << 1) + fq);
  float4 v[8];
#pragma unroll
  for (int it = 0; it < 8; ++it)
    v[it] = xv[base4 + (size_t)(t0 + (it << 7)) * 8];
#pragma unroll
  for (int it = 0; it < 8; ++it) {
    int t = t0 + (it << 7);
    sm[((fq << 1) + 0) * 1024 + t] = pkrtz(v[it].x, v[it].y);
    sm[((fq << 1) + 1) * 1024 + t] = pkrtz(v[it].z, v[it].w);
  }
  __syncthreads();

  // packed series pair: lo = f8*8 + 2*wv, hi = +1
  uint p[16];
  {
    const uint* src = sm + (wv << 10);
#pragma unroll
    for (int q = 0; q < 4; ++q) {
      uint4 vv = *(const uint4*)(src + (q << 8) + (lane << 2));
      p[q * 4 + 0] = vv.x; p[q * 4 + 1] = vv.y;
      p[q * 4 + 2] = vv.z; p[q * 4 + 3] = vv.w;
    }
  }

  const int addr_nx = ((lane + 1) & 63) << 2;
  const int addr63  = (lane ^ 63) << 2;
  const bool is63 = (lane == 63);

  // ============== packed per-series stats (both series at once) ===========
  // tb values at t = 0, 256, 512, 767, 1023 (packed, uniform)
  uint tb0p = irdl(p[0], 0);
  uint tb1p = irdl(p[4], 0);
  uint tb2p = irdl(p[8], 0);
  uint tb3p = irdl(p[11], 63);
  uint tb4p = irdl(p[15], 63);

  // raw moments, packed f16
  h2 s1h = {0, 0}, s2h = {0, 0}, s3h = {0, 0}, s4h = {0, 0};
#pragma unroll
  for (int r = 0; r < 16; ++r) {
    h2 vh = u2h(p[r]);
    h2 v2 = vh * vh;
    s1h += vh;
    s2h += v2;
    s3h += v2 * vh;
    s4h += v2 * v2;
  }
  uint s1r = red_sum_pk(h2u(s1h));
  const _Float16 inv1024 = (_Float16)(1.0f / 1024.0f);
  h2 invv = {inv1024, inv1024};
  uint meanp = irdl(h2u(u2h(s1r) * invv), 0);

  // counts: 1 v_cmp_gt_f16 per series per reg; hi half via one lshr per reg
  const uint tb0hh = tb0p >> 16, tb1hh = tb1p >> 16, tb2hh = tb2p >> 16;
  const uint tb3hh = tb3p >> 16, tb4hh = tb4p >> 16, meanhh = meanp >> 16;
  int cposA = 0, cposB = 0, cmA = 0, cmB = 0;
  int c0A = 0, c0B = 0, c1A = 0, c1B = 0, c2A = 0, c2B = 0;
  int c3A = 0, c3B = 0, c4A = 0, c4B = 0;
#pragma unroll
  for (int r = 0; r < 16; ++r) {
    _Float16 a = u2h(p[r]).x;
    _Float16 bb = u2h(p[r] >> 16).x;
    cposA += __popcll(__ballot(a > (_Float16)0));
    cposB += __popcll(__ballot(bb > (_Float16)0));
    cmA += __popcll(__ballot(a > u2h(meanp).x));
    cmB += __popcll(__ballot(bb > u2h(meanhh).x));
    c0A += __popcll(__ballot(a > u2h(tb0p).x));
    c0B += __popcll(__ballot(bb > u2h(tb0hh).x));
    c1A += __popcll(__ballot(a > u2h(tb1p).x));
    c1B += __popcll(__ballot(bb > u2h(tb1hh).x));
    c2A += __popcll(__ballot(a > u2h(tb2p).x));
    c2B += __popcll(__ballot(bb > u2h(tb2hh).x));
    c3A += __popcll(__ballot(a > u2h(tb3p).x));
    c3B += __popcll(__ballot(bb > u2h(tb3hh).x));
    c4A += __popcll(__ballot(a > u2h(tb4p).x));
    c4B += __popcll(__ballot(bb > u2h(tb4hh).x));
  }

  // diffs d_t = x[t]-x[t+1], t in [1,1022], packed; sum telescopes.
  uint j1 = irdl(p[4], 0), j2 = irdl(p[8], 0), j3 = irdl(p[12], 0);
  h2 sadh = {0, 0}, sddh = {0, 0};
#pragma unroll
  for (int q = 0; q < 4; ++q) {
    uint nv = bpermu(addr_nx, p[q * 4]);
    if (q == 0) nv = is63 ? j1 : nv;
    if (q == 1) nv = is63 ? j2 : nv;
    if (q == 2) nv = is63 ? j3 : nv;
#pragma unroll
    for (int i = 0; i < 4; ++i) {
      uint xn = (i < 3) ? p[q * 4 + i + 1] : nv;
      uint dvu = h2u(u2h(p[q * 4 + i]) - u2h(xn));
      if (q == 0 && i == 0) dvu = csel(dvu, 0u, KML0);   // t=0 excluded
      if (q == 3 && i == 3) dvu = csel(dvu, 0u, KML63);  // t=1023 excluded
      h2 dv = u2h(dvu);
      sadh += u2h(dvu & 0x7FFF7FFFu);
      sddh += dv * dv;
    }
  }
  uint s2r = red_sum_pk(h2u(s2h));
  uint s3r = red_sum_pk(h2u(s3h));
  uint s4r = red_sum_pk(h2u(s4h));
  uint sadr = red_sum_pk(h2u(sadh));
  uint sddr = red_sum_pk(h2u(sddh));
  uint x1p = irdl(p[1], 0), x1023p = irdl(p[15], 63);
  uint SDp = irdl(h2u(u2h(x1p) - u2h(x1023p)), 0);

  // ================= packed sort (both series at once) =====================
  sort16p(p);
  splitp<1>(p, KM1);  merge16p(p);
  splitp<3>(p, KM2);  xstp<1>(p, KM1); merge16p(p);
  splitp<7>(p, KM4);  xstp<2>(p, KM2); xstp<1>(p, KM1); merge16p(p);
  splitp<15>(p, KM8); xstp<4>(p, KM4); xstp<2>(p, KM2); xstp<1>(p, KM1);
  merge16p(p);
  splitp<31>(p, KM16); xstp<8>(p, KM8); xstp<4>(p, KM4); xstp<2>(p, KM2);
  xstp<1>(p, KM1); merge16p(p);
  split63p(p, KM32, addr63);
  xstp<16>(p, KM16);

  // Pruned tail: 16-lane groups hold rank blocks {0-255,256-511,512-767,768-1023}.
  uint mnv = p[0], mxv = p[0];
#pragma unroll
  for (int r = 1; r < 16; ++r) { mnv = pmin(mnv, p[r]); mxv = pmax(mxv, p[r]); }
  mnv = pmin(mnv, exu<1>(mnv)); mxv = pmax(mxv, exu<1>(mxv));
  mnv = pmin(mnv, exu<2>(mnv)); mxv = pmax(mxv, exu<2>(mxv));
  mnv = pmin(mnv, exu<4>(mnv)); mxv = pmax(mxv, exu<4>(mxv));
  mnv = pmin(mnv, exu<8>(mnv)); mxv = pmax(mxv, exu<8>(mxv));

  uint g0n = irdl(mnv, 0);    // rank 0    (min)
  uint g1n = irdl(mnv, 16);   // rank 256  (q1)
  uint g2n = irdl(mnv, 32);   // rank 512  (q2)
  uint g2x = irdl(mxv, 32);   // rank 767  (q3)
  uint g3x = irdl(mxv, 48);   // rank 1023 (max)

  // ---- per-wave epilogue: lanes 0/1 each compute one series' 30 features ----
  // (all inputs are wave-uniform readlane/ballot results; lane0 = lo series,
  //  lane1 = hi series)
  if (lane < 2) {
    const int sh = lane << 4;
    float mnf  = (float)u2h(g0n >> sh).x;
    float q1f  = (float)u2h(g1n >> sh).x;
    float q2f  = (float)u2h(g2n >> sh).x;
    float q3f  = (float)u2h(g2x >> sh).x;
    float mxf  = (float)u2h(g3x >> sh).x;
    float mean = (float)u2h(meanp >> sh).x;
    float s2   = (float)u2h(s2r >> sh).x;
    float s3   = (float)u2h(s3r >> sh).x;
    float s4   = (float)u2h(s4r >> sh).x;
    float sad  = (float)u2h(sadr >> sh).x;
    float sdd  = (float)u2h(sddr >> sh).x;
    float SD   = (float)u2h(SDp >> sh).x;
    float tb0  = (float)u2h(tb0p >> sh).x;
    float tb1  = (float)u2h(tb1p >> sh).x;
    float tb2  = (float)u2h(tb2p >> sh).x;
    float tb3  = (float)u2h(tb3p >> sh).x;
    float tb4  = (float)u2h(tb4p >> sh).x;
    float fcpos = (float)(lane ? cposB : cposA);
    float fcm   = (float)(lane ? cmB : cmA);
    float fc0   = (float)(lane ? c0B : c0A);
    float fc1   = (float)(lane ? c1B : c1A);
    float fc2   = (float)(lane ? c2B : c2A);
    float fc3   = (float)(lane ? c3B : c3A);
    float fc4   = (float)(lane ? c4B : c4A);

    float ex2 = s2 * (1.0f / 1024.0f);
    float rms = __builtin_amdgcn_sqrtf(fmaxf(ex2, 0.f));
    float var = fmaxf(ex2 - mean * mean, 0.f);
    float stdv = __builtin_amdgcn_sqrtf(var);
    float m2 = mean * mean;
    float m3c = s3 - 3.f * mean * s2 + 2048.f * m2 * mean;
    const float coef3 = (float)(1024.0 / (1023.0 * 1022.0));
    float den3 = stdv * stdv * stdv;
    float skew = (den3 > 0.f) ? coef3 * m3c * __builtin_amdgcn_rcpf(den3) : 0.f;
    float k4c = s4 - 4.f * mean * s3 + 6.f * m2 * s2 - 3072.f * m2 * m2;
    float s2c = s2 - 1024.f * m2;
    float k22 = s2c * s2c;
    const float alpha = (float)(1024.0 * 1025.0 * 1023.0 / (1022.0 * 1021.0));
    const float rightc = (float)(3.0 * 1023.0 * 1023.0 / (1022.0 * 1021.0));
    float kurt = (k22 > 0.f) ? alpha * k4c * __builtin_amdgcn_rcpf(k22) - rightc
                             : -rightc;

    float* o = stash + ((wv << 1) + lane) * 30;
    o[0] = mean;  o[1] = mnf;  o[2] = mxf;
    o[3] = rms;   o[4] = var;  o[5] = stdv;
    o[6] = skew;  o[7] = kurt;
    o[8] = SD * (1.0f / 1022.0f);
    o[9] = SD;
    o[10] = sad * (1.0f / 1022.0f);
    o[11] = q1f;  o[12] = q2f; o[13] = q3f;
    o[14] = tb0;  o[15] = tb1; o[16] = tb2; o[17] = tb3; o[18] = tb4;
    o[19] = s2;
    o[20] = fmaxf(fabsf(mnf), fabsf(mxf));
    o[21] = sad;
    o[22] = __builtin_amdgcn_sqrtf(fmaxf(sdd, 0.f));
    o[23] = fcpos; o[24] = fcm;
    o[25] = fc0;   o[26] = fc1; o[27] = fc2; o[28] = fc3; o[29] = fc4;
  }
  __syncthreads();

  // ---- coalesced block output: 8 rows x 30 floats = 960 B contiguous ----
  if (tid < 240) {
    size_t base = ((size_t)((b << 5) + (f8 << 3))) * 30;
    out[base + tid] = stash[tid];
  }
}

extern "C" void kernel_launch(void* const* d_in, const int* in_sizes, int n_in,
                              void* d_out, int out_size, void* d_ws, size_t ws_size,
                              hipStream_t stream) {
  const float* x = (const float*)d_in[0];
  float* out = (float*)d_out;
  hipLaunchKernelGGL(feat_fused, dim3(2048), dim3(256), 0, stream, x, out);
}